// Round 2
// baseline (959.701 us; speedup 1.0000x reference)
//
#include <hip/hip_runtime.h>
#include <stdint.h>

#define KW   128   // u32 words per row (4096 bits)
#define BT   128   // output tile dim (rows and cols)
#define NCK  4     // K-chunks: 4 x 32 words = 128 words
// per chunk: 8 uint4 per row

// ---------------------------------------------------------------------------
// Binarize: wave of 64 lanes reads 64 consecutive floats, ballot(v>0) gives a
// 64-bit mask in exact lane order; lane 0 stores the u64.
// ---------------------------------------------------------------------------
__global__ __launch_bounds__(256) void binarize64(const float* __restrict__ in,
                                                  unsigned long long* __restrict__ out,
                                                  int n64) {
    const int tid   = blockIdx.x * blockDim.x + threadIdx.x;
    const int lane  = threadIdx.x & 63;
    const int wave  = tid >> 6;
    const int nwav  = (gridDim.x * blockDim.x) >> 6;
    for (int w = wave; w < n64; w += nwav) {
        float v = in[(size_t)w * 64 + lane];
        unsigned long long m = __ballot(v > 0.0f);
        if (lane == 0) out[w] = m;
    }
}

// ---------------------------------------------------------------------------
// Binary GEMM: C[i][j] = 4096 - 2 * popcount(xb_row_i ^ wb_row_j)
// 128x128 tile, 256 threads (16x16), 8x8 micro-tile per thread.
// K chunked into 4 x 1024 bits; LDS 32 KB/block.
// LDS XOR swizzle at uint4 granularity: data chunk cw of row r stored at
// cw ^ ((r>>3)&7). Inner loop iterates raw chunk j (preserves read broadcast);
// swizzled base address = 2 VALU ops per j, element offsets are immediates.
// ---------------------------------------------------------------------------
__global__ __launch_bounds__(256, 3) void xnor_gemm(const uint32_t* __restrict__ xb,
                                                    const uint32_t* __restrict__ wb,
                                                    float* __restrict__ out) {
    __shared__ uint4 lA[BT * 8];   // 16 KB
    __shared__ uint4 lB[BT * 8];   // 16 KB

    const int tid  = threadIdx.x;
    const int brow = blockIdx.y;
    const int bcol = blockIdx.x;
    const int tx   = tid & 15;     // col group (8 cols)
    const int ty   = tid >> 4;     // row group (8 rows)
    const int ka   = ty & 7;       // swizzle key for this thread's A rows
    const int kb   = tx & 7;       // swizzle key for this thread's B rows

    // global bases in uint4 units (row stride = 32 uint4)
    const uint4* gA = (const uint4*)(xb + (size_t)(brow * BT) * KW);
    const uint4* gB = (const uint4*)(wb + (size_t)(bcol * BT) * KW);

    // staging decomposition: item idx -> (r, cw)
    const int sr = tid >> 3;             // rows handled: sr, sr+32, sr+64, sr+96
    const int scw = tid & 7;
    const int swz0 = scw ^ ((sr >> 3) & 7);

    uint32_t acc[8][8];
#pragma unroll
    for (int r = 0; r < 8; ++r)
#pragma unroll
        for (int c = 0; c < 8; ++c) acc[r][c] = 0;

    const uint4* pa = lA + ty * 64;      // this thread's A row-group base
    const uint4* pb = lB + tx * 64;      // this thread's B row-group base

    for (int ck = 0; ck < NCK; ++ck) {
        if (ck) __syncthreads();
        // ---- stage chunk ck: 1024 uint4 per matrix, 4 each per thread ------
#pragma unroll
        for (int k = 0; k < 4; ++k) {
            const int r   = sr + k * 32;
            const int pcw = scw ^ ((r >> 3) & 7);
            (void)swz0;
            lA[r * 8 + pcw] = gA[r * 32 + ck * 8 + scw];
            lB[r * 8 + pcw] = gB[r * 32 + ck * 8 + scw];
        }
        __syncthreads();

        // ---- compute: 8 j-steps, each 16 b128 reads + 512 xor/bcnt ---------
#pragma unroll 2
        for (int j = 0; j < 8; ++j) {
            const uint4* paj = pa + (j ^ ka);   // swizzled base (2 VALU)
            const uint4* pbj = pb + (j ^ kb);
            uint4 a[8], b[8];
#pragma unroll
            for (int r = 0; r < 8; ++r) a[r] = paj[r * 8];   // imm offsets
#pragma unroll
            for (int c = 0; c < 8; ++c) b[c] = pbj[c * 8];
#pragma unroll
            for (int r = 0; r < 8; ++r) {
#pragma unroll
                for (int c = 0; c < 8; ++c) {
                    acc[r][c] += __popc(a[r].x ^ b[c].x);
                    acc[r][c] += __popc(a[r].y ^ b[c].y);
                    acc[r][c] += __popc(a[r].z ^ b[c].z);
                    acc[r][c] += __popc(a[r].w ^ b[c].w);
                }
            }
        }
    }

    // ---- epilogue: dot = 4096 - 2*popc, float4 stores ----------------------
    const size_t N = 4096;
    const int gcol = bcol * BT + tx * 8;
#pragma unroll
    for (int r = 0; r < 8; ++r) {
        const size_t grow = (size_t)(brow * BT + ty * 8 + r);
        float4 o0, o1;
        o0.x = (float)(4096 - 2 * (int)acc[r][0]);
        o0.y = (float)(4096 - 2 * (int)acc[r][1]);
        o0.z = (float)(4096 - 2 * (int)acc[r][2]);
        o0.w = (float)(4096 - 2 * (int)acc[r][3]);
        o1.x = (float)(4096 - 2 * (int)acc[r][4]);
        o1.y = (float)(4096 - 2 * (int)acc[r][5]);
        o1.z = (float)(4096 - 2 * (int)acc[r][6]);
        o1.w = (float)(4096 - 2 * (int)acc[r][7]);
        *(float4*)(out + grow * N + gcol)     = o0;
        *(float4*)(out + grow * N + gcol + 4) = o1;
    }
}

extern "C" void kernel_launch(void* const* d_in, const int* in_sizes, int n_in,
                              void* d_out, int out_size, void* d_ws, size_t ws_size,
                              hipStream_t stream) {
    const float* x = (const float*)d_in[0];   // [4096, 4096]
    const float* W = (const float*)d_in[1];   // [4096, 4096] (out, in)
    float* out = (float*)d_out;               // [4096, 4096] f32

    uint32_t* xb = (uint32_t*)d_ws;            // 2 MB
    uint32_t* wb = xb + (size_t)4096 * KW;     // next 2 MB

    const int n64 = 4096 * 4096 / 64;
    binarize64<<<2048, 256, 0, stream>>>(x, (unsigned long long*)xb, n64);
    binarize64<<<2048, 256, 0, stream>>>(W, (unsigned long long*)wb, n64);

    dim3 grid(4096 / BT, 4096 / BT);           // 32 x 32 blocks
    xnor_gemm<<<grid, 256, 0, stream>>>(xb, wb, out);
}

// Round 3
// 531.473 us; speedup vs baseline: 1.8057x; 1.8057x over previous
//
#include <hip/hip_runtime.h>
#include <stdint.h>

#define KW   128   // u32 words per row (4096 bits)
#define BM   128   // tile rows (tokens)
#define BN    64   // tile cols (out features)
#define NCK    4   // K chunks of 8 uint4 (1024 bits) each

// ---------------------------------------------------------------------------
// Binarize: wave of 64 lanes reads 64 consecutive floats, ballot(v>0) gives a
// 64-bit mask in exact lane order; lane 0 stores the u64.
// ---------------------------------------------------------------------------
__global__ __launch_bounds__(256) void binarize64(const float* __restrict__ in,
                                                  unsigned long long* __restrict__ out,
                                                  int n64) {
    const int tid   = blockIdx.x * blockDim.x + threadIdx.x;
    const int lane  = threadIdx.x & 63;
    const int wave  = tid >> 6;
    const int nwav  = (gridDim.x * blockDim.x) >> 6;
    for (int w = wave; w < n64; w += nwav) {
        float v = in[(size_t)w * 64 + lane];
        unsigned long long m = __ballot(v > 0.0f);
        if (lane == 0) out[w] = m;
    }
}

// ---------------------------------------------------------------------------
// Binary GEMM: C[i][j] = 4096 - 2 * popcount(row_i(xb) ^ row_j(wb))
// 128x64 tile, 256 threads (16 col-groups x 16 row-groups), 8x4 micro-tile.
// K chunked: 4 x 1024 bits, LDS 24 KB/block.
// LDS XOR swizzle, 4-row granularity: data chunk cw of row r stored at
// cw ^ ((r>>2)&7). B-operand reads (16 distinct rows/wave) -> 2-way max;
// A-operand reads are 4-address broadcasts on distinct bank groups.
// Register budget: acc 32 + a 32 + b 16 + addr ~= 100 -> no spill at cap 128.
// ---------------------------------------------------------------------------
__global__ __launch_bounds__(256, 4) void xnor_gemm(const uint32_t* __restrict__ xb,
                                                    const uint32_t* __restrict__ wb,
                                                    float* __restrict__ out) {
    __shared__ uint4 lA[BM * 8];   // 16 KB
    __shared__ uint4 lB[BN * 8];   // 8 KB

    const int tid  = threadIdx.x;
    const int brow = blockIdx.y;
    const int bcol = blockIdx.x;
    const int tx   = tid & 15;     // col group: 4 cols
    const int ty   = tid >> 4;     // row group: 8 rows

    // global bases in uint4 units (full row = 32 uint4)
    const uint4* gA = (const uint4*)xb + (size_t)(brow * BM) * 32;
    const uint4* gB = (const uint4*)wb + (size_t)(bcol * BN) * 32;

    // staging decomposition
    const int sr  = tid >> 3;      // 0..31
    const int scw = tid & 7;       // 0..7

    uint32_t acc[8][4];
#pragma unroll
    for (int r = 0; r < 8; ++r)
#pragma unroll
        for (int c = 0; c < 4; ++c) acc[r][c] = 0;

    const uint4* pa = lA + ty * 64;            // row ty*8 (8 uint4/row)
    const uint4* pb = lB + tx * 32;            // row tx*4
    const int ka0 = (ty * 2) & 7;              // key for micro rows 0..3
    const int ka1 = (ty * 2 + 1) & 7;          // key for micro rows 4..7
    const int kb  = tx & 7;                    // key for all 4 B rows

    for (int ck = 0; ck < NCK; ++ck) {
        if (ck) __syncthreads();
        // ---- stage chunk ck -------------------------------------------------
#pragma unroll
        for (int k = 0; k < 4; ++k) {          // A: 128 rows
            const int r = sr + k * 32;
            lA[r * 8 + (scw ^ ((r >> 2) & 7))] = gA[(size_t)r * 32 + ck * 8 + scw];
        }
#pragma unroll
        for (int k = 0; k < 2; ++k) {          // B: 64 rows
            const int r = sr + k * 32;
            lB[r * 8 + (scw ^ ((r >> 2) & 7))] = gB[(size_t)r * 32 + ck * 8 + scw];
        }
        __syncthreads();

        // ---- compute: 8 j-steps, each 12 b128 reads + 256 xor/bcnt ---------
#pragma unroll 1
        for (int j = 0; j < 8; ++j) {
            const uint4* pa0 = pa + (j ^ ka0);
            const uint4* pa1 = pa + 32 + (j ^ ka1);
            const uint4* pbj = pb + (j ^ kb);
            uint4 a[8], b[4];
#pragma unroll
            for (int r = 0; r < 4; ++r) a[r]     = pa0[r * 8];
#pragma unroll
            for (int r = 0; r < 4; ++r) a[4 + r] = pa1[r * 8];
#pragma unroll
            for (int c = 0; c < 4; ++c) b[c]     = pbj[c * 8];
#pragma unroll
            for (int r = 0; r < 8; ++r) {
#pragma unroll
                for (int c = 0; c < 4; ++c) {
                    acc[r][c] += __popc(a[r].x ^ b[c].x);
                    acc[r][c] += __popc(a[r].y ^ b[c].y);
                    acc[r][c] += __popc(a[r].z ^ b[c].z);
                    acc[r][c] += __popc(a[r].w ^ b[c].w);
                }
            }
        }
    }

    // ---- epilogue: dot = 4096 - 2*popc, float4 stores ----------------------
    const size_t N = 4096;
    const int gcol = bcol * BN + tx * 4;
#pragma unroll
    for (int r = 0; r < 8; ++r) {
        const size_t grow = (size_t)(brow * BM + ty * 8 + r);
        float4 o;
        o.x = (float)(4096 - 2 * (int)acc[r][0]);
        o.y = (float)(4096 - 2 * (int)acc[r][1]);
        o.z = (float)(4096 - 2 * (int)acc[r][2]);
        o.w = (float)(4096 - 2 * (int)acc[r][3]);
        *(float4*)(out + grow * N + gcol) = o;
    }
}

extern "C" void kernel_launch(void* const* d_in, const int* in_sizes, int n_in,
                              void* d_out, int out_size, void* d_ws, size_t ws_size,
                              hipStream_t stream) {
    const float* x = (const float*)d_in[0];   // [4096, 4096]
    const float* W = (const float*)d_in[1];   // [4096, 4096] (out, in)
    float* out = (float*)d_out;               // [4096, 4096] f32

    uint32_t* xb = (uint32_t*)d_ws;            // 2 MB
    uint32_t* wb = xb + (size_t)4096 * KW;     // next 2 MB

    const int n64 = 4096 * 4096 / 64;
    binarize64<<<2048, 256, 0, stream>>>(x, (unsigned long long*)xb, n64);
    binarize64<<<2048, 256, 0, stream>>>(W, (unsigned long long*)wb, n64);

    dim3 grid(4096 / BN, 4096 / BM);           // 64 x 32 blocks
    xnor_gemm<<<grid, 256, 0, stream>>>(xb, wb, out);
}

// Round 4
// 160.357 us; speedup vs baseline: 5.9848x; 3.3143x over previous
//
#include <hip/hip_runtime.h>
#include <stdint.h>

#define KW   128   // u32 words per row (4096 bits)
#define BT   128   // output tile dim (rows and cols)
#define NCK    4   // K chunks: 4 x 8 uint4 (1024 bits) each

// ---------------------------------------------------------------------------
// Binarize: wave of 64 lanes reads 64 consecutive floats, ballot(v>0) gives a
// 64-bit mask in exact lane order; lane 0 stores the u64. (~3 us, L3-resident)
// ---------------------------------------------------------------------------
__global__ __launch_bounds__(256) void binarize64(const float* __restrict__ in,
                                                  unsigned long long* __restrict__ out,
                                                  int n64) {
    const int tid   = blockIdx.x * blockDim.x + threadIdx.x;
    const int lane  = threadIdx.x & 63;
    const int wave  = tid >> 6;
    const int nwav  = (gridDim.x * blockDim.x) >> 6;
    for (int w = wave; w < n64; w += nwav) {
        float v = in[(size_t)w * 64 + lane];
        unsigned long long m = __ballot(v > 0.0f);
        if (lane == 0) out[w] = m;
    }
}

// forced popcount-accumulate: D = popcount(S0) + D  (one VOP3 inst)
static __device__ __forceinline__ void pacc(uint32_t& acc, uint32_t x, uint32_t y) {
    uint32_t t = x ^ y;
    asm("v_bcnt_u32_b32 %0, %1, %0" : "+v"(acc) : "v"(t));
}

// ---------------------------------------------------------------------------
// Binary GEMM: C[i][j] = 4096 - 2 * popcount(row_i(xb) ^ row_j(wb))
// 128x128 tile, 256 threads (16x16), 8x8 micro-tile. K chunked: 4 x 1024 bits,
// LDS 32 KB. NO launch_bounds occupancy hint (R2/R3: hint -> half-budget
// alloc -> scratch spill).
// LDS swizzle: chunk cw of row r stored at cw ^ ((r>>3)&7). All 8 rows of a
// thread's micro-tile share one key (ty&7 / tx&7) -> per-j addressing is two
// v_xor; element offsets are immediates. B reads: 16 distinct rows/wave spread
// over all 8 bank-groups (2-way = free). A reads: 4-address broadcast.
// ---------------------------------------------------------------------------
__global__ __launch_bounds__(256) void xnor_gemm(const uint32_t* __restrict__ xb,
                                                 const uint32_t* __restrict__ wb,
                                                 float* __restrict__ out) {
    __shared__ uint4 lA[BT * 8];   // 16 KB
    __shared__ uint4 lB[BT * 8];   // 16 KB

    const int tid  = threadIdx.x;
    const int brow = blockIdx.y;
    const int bcol = blockIdx.x;
    const int tx   = tid & 15;     // col group: 8 cols
    const int ty   = tid >> 4;     // row group: 8 rows

    // global bases in uint4 units (full row = 32 uint4)
    const uint4* gA = (const uint4*)xb + (size_t)(brow * BT) * 32;
    const uint4* gB = (const uint4*)wb + (size_t)(bcol * BT) * 32;

    // staging decomposition: 1024 uint4 per matrix per chunk, 4 each/thread
    const int sr  = tid >> 3;      // 0..31
    const int scw = tid & 7;       // 0..7

    uint32_t acc[8][8];
#pragma unroll
    for (int r = 0; r < 8; ++r)
#pragma unroll
        for (int c = 0; c < 8; ++c) acc[r][c] = 0;

    const uint4* pa = lA + ty * 64;    // row ty*8, 8 uint4/row
    const uint4* pb = lB + tx * 64;    // row tx*8
    const int ka = ty & 7;             // shared key for A rows ty*8..+7
    const int kb = tx & 7;             // shared key for B rows tx*8..+7

    for (int ck = 0; ck < NCK; ++ck) {
        if (ck) __syncthreads();
#pragma unroll
        for (int k = 0; k < 4; ++k) {
            const int r   = sr + k * 32;
            const int pcw = scw ^ ((r >> 3) & 7);
            lA[r * 8 + pcw] = gA[(size_t)r * 32 + ck * 8 + scw];
            lB[r * 8 + pcw] = gB[(size_t)r * 32 + ck * 8 + scw];
        }
        __syncthreads();

        // ---- compute: 8 j-steps; per j: 16 b128 reads + 512 xor/bcnt -------
#pragma unroll 1
        for (int j = 0; j < 8; ++j) {
            const uint4* paj = pa + (j ^ ka);   // 1 v_xor
            const uint4* pbj = pb + (j ^ kb);   // 1 v_xor
            uint4 a[8], b[4];
#pragma unroll
            for (int r = 0; r < 8; ++r) a[r] = paj[r * 8];   // imm offsets
            // first half of B columns
#pragma unroll
            for (int c = 0; c < 4; ++c) b[c] = pbj[c * 8];
#pragma unroll
            for (int r = 0; r < 8; ++r)
#pragma unroll
                for (int c = 0; c < 4; ++c) {
                    pacc(acc[r][c], a[r].x, b[c].x);
                    pacc(acc[r][c], a[r].y, b[c].y);
                    pacc(acc[r][c], a[r].z, b[c].z);
                    pacc(acc[r][c], a[r].w, b[c].w);
                }
            // second half of B columns (b reused -> live set stays ~135)
#pragma unroll
            for (int c = 0; c < 4; ++c) b[c] = pbj[(c + 4) * 8];
#pragma unroll
            for (int r = 0; r < 8; ++r)
#pragma unroll
                for (int c = 0; c < 4; ++c) {
                    pacc(acc[r][c + 4], a[r].x, b[c].x);
                    pacc(acc[r][c + 4], a[r].y, b[c].y);
                    pacc(acc[r][c + 4], a[r].z, b[c].z);
                    pacc(acc[r][c + 4], a[r].w, b[c].w);
                }
        }
    }

    // ---- epilogue: dot = 4096 - 2*popc, float4 stores ----------------------
    const size_t N = 4096;
    const int gcol = bcol * BT + tx * 8;
#pragma unroll
    for (int r = 0; r < 8; ++r) {
        const size_t grow = (size_t)(brow * BT + ty * 8 + r);
        float4 o0, o1;
        o0.x = (float)(4096 - 2 * (int)acc[r][0]);
        o0.y = (float)(4096 - 2 * (int)acc[r][1]);
        o0.z = (float)(4096 - 2 * (int)acc[r][2]);
        o0.w = (float)(4096 - 2 * (int)acc[r][3]);
        o1.x = (float)(4096 - 2 * (int)acc[r][4]);
        o1.y = (float)(4096 - 2 * (int)acc[r][5]);
        o1.z = (float)(4096 - 2 * (int)acc[r][6]);
        o1.w = (float)(4096 - 2 * (int)acc[r][7]);
        *(float4*)(out + grow * N + gcol)     = o0;
        *(float4*)(out + grow * N + gcol + 4) = o1;
    }
}

extern "C" void kernel_launch(void* const* d_in, const int* in_sizes, int n_in,
                              void* d_out, int out_size, void* d_ws, size_t ws_size,
                              hipStream_t stream) {
    const float* x = (const float*)d_in[0];   // [4096, 4096]
    const float* W = (const float*)d_in[1];   // [4096, 4096] (out, in)
    float* out = (float*)d_out;               // [4096, 4096] f32

    uint32_t* xb = (uint32_t*)d_ws;            // 2 MB
    uint32_t* wb = xb + (size_t)4096 * KW;     // next 2 MB

    const int n64 = 4096 * 4096 / 64;
    binarize64<<<2048, 256, 0, stream>>>(x, (unsigned long long*)xb, n64);
    binarize64<<<2048, 256, 0, stream>>>(W, (unsigned long long*)wb, n64);

    dim3 grid(4096 / BT, 4096 / BT);           // 32 x 32 blocks
    xnor_gemm<<<grid, 256, 0, stream>>>(xb, wb, out);
}

// Round 5
// 158.615 us; speedup vs baseline: 6.0505x; 1.0110x over previous
//
#include <hip/hip_runtime.h>
#include <stdint.h>

#define KW   128   // u32 words per row (4096 bits)
#define BM   128   // tile rows (tokens)
#define BN    64   // tile cols (out features)
#define NCK    4   // K chunks: 4 x 8 uint4 (1024 bits) each

// ---------------------------------------------------------------------------
// Binarize: wave of 64 lanes reads 64 consecutive floats, ballot(v>0) gives a
// 64-bit mask in exact lane order; lane 0 stores the u64.
// ---------------------------------------------------------------------------
__global__ __launch_bounds__(256) void binarize64(const float* __restrict__ in,
                                                  unsigned long long* __restrict__ out,
                                                  int n64) {
    const int tid   = blockIdx.x * blockDim.x + threadIdx.x;
    const int lane  = threadIdx.x & 63;
    const int wave  = tid >> 6;
    const int nwav  = (gridDim.x * blockDim.x) >> 6;
    for (int w = wave; w < n64; w += nwav) {
        float v = in[(size_t)w * 64 + lane];
        unsigned long long m = __ballot(v > 0.0f);
        if (lane == 0) out[w] = m;
    }
}

// forced popcount-accumulate: D = popcount(S0) + D  (one VOP3 inst).
// Safe ONLY when acc lives in an arch VGPR (launch_bounds(256,2) -> allocator
// sizes arch budget to live set; R4 showed the no-hint default splits 64 arch
// + AGPR and inserts accvgpr copies around this asm = 2x VALU).
static __device__ __forceinline__ void pacc(uint32_t& acc, uint32_t x, uint32_t y) {
    uint32_t t = x ^ y;
    asm("v_bcnt_u32_b32 %0, %1, %0" : "+v"(acc) : "v"(t));
}

// ---------------------------------------------------------------------------
// Binary GEMM: C[i][j] = 4096 - 2 * popcount(row_i(xb) ^ row_j(wb))
// 128x64 tile, 256 threads (16x16), 8x4 micro-tile. K chunked: 4 x 1024 bits,
// LDS 24 KB. Live set ~100 VGPR -> pure arch-VGPR allocation at (256,2).
// LDS swizzle: chunk cw of row r stored at cw ^ ((r>>3)&7). Thread's 8 A rows
// share key ty&7; its 4 B rows share key tx>>1 -> per-j addressing is two
// v_xor, element offsets are immediates.
// ---------------------------------------------------------------------------
__global__ __launch_bounds__(256, 2) void xnor_gemm(const uint32_t* __restrict__ xb,
                                                    const uint32_t* __restrict__ wb,
                                                    float* __restrict__ out) {
    __shared__ uint4 lA[BM * 8];   // 16 KB
    __shared__ uint4 lB[BN * 8];   // 8 KB

    const int tid  = threadIdx.x;
    const int brow = blockIdx.y;
    const int bcol = blockIdx.x;
    const int tx   = tid & 15;     // col group: 4 cols
    const int ty   = tid >> 4;     // row group: 8 rows

    // global bases in uint4 units (full row = 32 uint4)
    const uint4* gA = (const uint4*)xb + (size_t)(brow * BM) * 32;
    const uint4* gB = (const uint4*)wb + (size_t)(bcol * BN) * 32;

    // staging decomposition
    const int sr  = tid >> 3;      // 0..31
    const int scw = tid & 7;       // 0..7

    uint32_t acc[8][4];
#pragma unroll
    for (int r = 0; r < 8; ++r)
#pragma unroll
        for (int c = 0; c < 4; ++c) acc[r][c] = 0;

    const uint4* pa = lA + ty * 64;    // row ty*8, 8 uint4/row
    const uint4* pb = lB + tx * 32;    // row tx*4
    const int ka = ty & 7;             // shared swizzle key for 8 A rows
    const int kb = tx >> 1;            // shared swizzle key for 4 B rows

    for (int ck = 0; ck < NCK; ++ck) {
        if (ck) __syncthreads();
#pragma unroll
        for (int k = 0; k < 4; ++k) {          // A: 128 rows
            const int r = sr + k * 32;
            lA[r * 8 + (scw ^ ((r >> 3) & 7))] = gA[(size_t)r * 32 + ck * 8 + scw];
        }
#pragma unroll
        for (int k = 0; k < 2; ++k) {          // B: 64 rows
            const int r = sr + k * 32;
            lB[r * 8 + (scw ^ ((r >> 3) & 7))] = gB[(size_t)r * 32 + ck * 8 + scw];
        }
        __syncthreads();

        // ---- compute: 8 j-steps; per j: 12 b128 reads + 512 VALU -----------
#pragma unroll 1
        for (int j = 0; j < 8; ++j) {
            const uint4* paj = pa + (j ^ ka);   // 1 v_xor
            const uint4* pbj = pb + (j ^ kb);   // 1 v_xor
            uint4 a[8], b[4];
#pragma unroll
            for (int r = 0; r < 8; ++r) a[r] = paj[r * 8];   // imm offsets
#pragma unroll
            for (int c = 0; c < 4; ++c) b[c] = pbj[c * 8];
#pragma unroll
            for (int r = 0; r < 8; ++r)
#pragma unroll
                for (int c = 0; c < 4; ++c) {
                    pacc(acc[r][c], a[r].x, b[c].x);
                    pacc(acc[r][c], a[r].y, b[c].y);
                    pacc(acc[r][c], a[r].z, b[c].z);
                    pacc(acc[r][c], a[r].w, b[c].w);
                }
        }
    }

    // ---- epilogue: dot = 4096 - 2*popc, float4 stores ----------------------
    const size_t N = 4096;
    const int gcol = bcol * BN + tx * 4;
#pragma unroll
    for (int r = 0; r < 8; ++r) {
        const size_t grow = (size_t)(brow * BM + ty * 8 + r);
        float4 o;
        o.x = (float)(4096 - 2 * (int)acc[r][0]);
        o.y = (float)(4096 - 2 * (int)acc[r][1]);
        o.z = (float)(4096 - 2 * (int)acc[r][2]);
        o.w = (float)(4096 - 2 * (int)acc[r][3]);
        *(float4*)(out + grow * N + gcol) = o;
    }
}

extern "C" void kernel_launch(void* const* d_in, const int* in_sizes, int n_in,
                              void* d_out, int out_size, void* d_ws, size_t ws_size,
                              hipStream_t stream) {
    const float* x = (const float*)d_in[0];   // [4096, 4096]
    const float* W = (const float*)d_in[1];   // [4096, 4096] (out, in)
    float* out = (float*)d_out;               // [4096, 4096] f32

    uint32_t* xb = (uint32_t*)d_ws;            // 2 MB
    uint32_t* wb = xb + (size_t)4096 * KW;     // next 2 MB

    const int n64 = 4096 * 4096 / 64;
    binarize64<<<2048, 256, 0, stream>>>(x, (unsigned long long*)xb, n64);
    binarize64<<<2048, 256, 0, stream>>>(W, (unsigned long long*)wb, n64);

    dim3 grid(4096 / BN, 4096 / BM);           // 64 x 32 blocks
    xnor_gemm<<<grid, 256, 0, stream>>>(xb, wb, out);
}